// Round 1
// baseline (939.359 us; speedup 1.0000x reference)
//
#include <hip/hip_runtime.h>
#include <math.h>

#define B 64
#define T 4096
#define H 256
#define D 128
#define O 128
#define EPS 1e-5f

#define TT 32        // t-tile per block in scores kernel
#define TCHUNK 16    // t-chunks for context partials

// ---------------- K1: hid_proj = h_prev @ W_h^T + attn_b ; gh = h_prev @ W_hh^T + b_hh ----
__global__ __launch_bounds__(256) void k1_hidproj_gh(
    const float* __restrict__ last_hidden, const float* __restrict__ attn_W,
    const float* __restrict__ attn_b, const float* __restrict__ W_hh,
    const float* __restrict__ b_hh, float* __restrict__ hid_proj,
    float* __restrict__ gh) {
  int b = blockIdx.x;
  int g = threadIdx.x;  // 0..255
  __shared__ float hp[H];
  hp[g] = last_hidden[b * H + g];
  __syncthreads();
  // hid_proj
  const float* wr = attn_W + (size_t)g * (2 * H);  // W_h row g
  float acc = attn_b[g];
#pragma unroll 4
  for (int h = 0; h < H; ++h) acc += hp[h] * wr[h];
  hid_proj[b * H + g] = acc;
  // gh: rows g, g+H, g+2H
#pragma unroll
  for (int k = 0; k < 3; ++k) {
    int row = k * H + g;
    const float* whr = W_hh + (size_t)row * H;
    float a2 = b_hh[row];
#pragma unroll 4
    for (int h = 0; h < H; ++h) a2 += hp[h] * whr[h];
    gh[(size_t)b * (3 * H) + row] = a2;
  }
}

// ---------------- K2: fused scores[b,t] = sum_g v[g]*tanh(hid_proj[b,g] + enc[t,b,:]·W_e[g,:]) ----
__global__ __launch_bounds__(256) void k2_scores(
    const float* __restrict__ enc, const float* __restrict__ attn_W,
    const float* __restrict__ hid_proj, const float* __restrict__ v,
    float* __restrict__ scores) {
  const int t0 = blockIdx.x * TT;
  const int b = blockIdx.y;
  const int tid = threadIdx.x;
  __shared__ float encs[TT][H];  // 32KB

  // cooperative load of enc tile: rows (t0..t0+31) for batch b
  const int F4 = H / 4;  // 64 float4 per row
#pragma unroll
  for (int it = 0; it < TT * F4 / 256; ++it) {  // 8 iters
    int idx = it * 256 + tid;
    int t = idx / F4;
    int h4 = idx % F4;
    float4 e = *reinterpret_cast<const float4*>(
        enc + ((size_t)(t0 + t) * B + b) * H + h4 * 4);
    *reinterpret_cast<float4*>(&encs[t][h4 * 4]) = e;
  }
  __syncthreads();

  const int g = tid;
  const float4* wr =
      reinterpret_cast<const float4*>(attn_W + (size_t)g * (2 * H) + H);
  float acc[TT];
#pragma unroll
  for (int t = 0; t < TT; ++t) acc[t] = 0.f;

#pragma unroll 2
  for (int h4 = 0; h4 < F4; ++h4) {
    float4 w = wr[h4];
#pragma unroll
    for (int t = 0; t < TT; ++t) {
      float4 e = *reinterpret_cast<const float4*>(&encs[t][h4 * 4]);
      acc[t] += w.x * e.x + w.y * e.y + w.z * e.z + w.w * e.w;
    }
  }

  float hpv = hid_proj[b * H + g];
  float vg = v[g];
  float val[TT];
#pragma unroll
  for (int t = 0; t < TT; ++t) val[t] = vg * tanhf(hpv + acc[t]);

  // reduce over 256 threads (g) for each t: wave shuffle then cross-wave LDS
#pragma unroll
  for (int t = 0; t < TT; ++t) {
    float x = val[t];
    for (int off = 32; off > 0; off >>= 1) x += __shfl_xor(x, off);
    val[t] = x;
  }
  __shared__ float part[4][TT];
  int wave = tid >> 6, lane = tid & 63;
  if (lane == 0) {
#pragma unroll
    for (int t = 0; t < TT; ++t) part[wave][t] = val[t];
  }
  __syncthreads();
  if (tid < TT) {
    float s = part[0][tid] + part[1][tid] + part[2][tid] + part[3][tid];
    scores[(size_t)b * T + t0 + tid] = s;
  }
}

// ---------------- K3: softmax over T per b; writes attn_weights to output ----
__global__ __launch_bounds__(256) void k3_softmax(
    const float* __restrict__ scores, float* __restrict__ attn_out) {
  int b = blockIdx.x;
  int tid = threadIdx.x;
  float vals[16];
  const float4* sp = reinterpret_cast<const float4*>(scores + (size_t)b * T);
#pragma unroll
  for (int i = 0; i < 4; ++i) {
    float4 x = sp[i * 256 + tid];
    vals[i * 4 + 0] = x.x; vals[i * 4 + 1] = x.y;
    vals[i * 4 + 2] = x.z; vals[i * 4 + 3] = x.w;
  }
  float m = -INFINITY;
#pragma unroll
  for (int i = 0; i < 16; ++i) m = fmaxf(m, vals[i]);
  for (int off = 32; off > 0; off >>= 1) m = fmaxf(m, __shfl_xor(m, off));
  __shared__ float redm[4];
  int wave = tid >> 6, lane = tid & 63;
  if (lane == 0) redm[wave] = m;
  __syncthreads();
  m = fmaxf(fmaxf(redm[0], redm[1]), fmaxf(redm[2], redm[3]));
  float s = 0.f;
#pragma unroll
  for (int i = 0; i < 16; ++i) {
    vals[i] = expf(vals[i] - m);
    s += vals[i];
  }
  for (int off = 32; off > 0; off >>= 1) s += __shfl_xor(s, off);
  __shared__ float reds[4];
  if (lane == 0) reds[wave] = s;
  __syncthreads();
  s = reds[0] + reds[1] + reds[2] + reds[3];
  float inv = 1.f / s;
  float4* op = reinterpret_cast<float4*>(attn_out + (size_t)b * T);
#pragma unroll
  for (int i = 0; i < 4; ++i) {
    float4 x;
    x.x = vals[i * 4 + 0] * inv; x.y = vals[i * 4 + 1] * inv;
    x.z = vals[i * 4 + 2] * inv; x.w = vals[i * 4 + 3] * inv;
    op[i * 256 + tid] = x;
  }
}

// ---------------- K4: context partials over t-chunks ----
__global__ __launch_bounds__(256) void k4_ctx_part(
    const float* __restrict__ enc, const float* __restrict__ attn_w,
    float* __restrict__ ctx_part) {
  int chunk = blockIdx.x;
  int b = blockIdx.y;
  int tid = threadIdx.x;
  int h4 = tid & 63;
  int tsub = tid >> 6;  // 0..3
  int tstart = chunk * (T / TCHUNK);
  float4 acc = {0.f, 0.f, 0.f, 0.f};
  const float* wrow = attn_w + (size_t)b * T;
  for (int t = tstart + tsub; t < tstart + T / TCHUNK; t += 4) {
    float w = wrow[t];
    float4 e = *reinterpret_cast<const float4*>(
        enc + ((size_t)t * B + b) * H + h4 * 4);
    acc.x += w * e.x; acc.y += w * e.y; acc.z += w * e.z; acc.w += w * e.w;
  }
  __shared__ float4 red[4][64];
  red[tsub][h4] = acc;
  __syncthreads();
  if (tid < 64) {
    float4 a = red[0][tid], b2 = red[1][tid], c = red[2][tid], d2 = red[3][tid];
    float4 r;
    r.x = a.x + b2.x + c.x + d2.x;
    r.y = a.y + b2.y + c.y + d2.y;
    r.z = a.z + b2.z + c.z + d2.z;
    r.w = a.w + b2.w + c.w + d2.w;
    *reinterpret_cast<float4*>(ctx_part + ((size_t)chunk * B + b) * H + tid * 4) = r;
  }
}

// ---------------- K5: x = concat(motion, context) @ pre_W^T + pre_b ----
__global__ __launch_bounds__(256) void k5_prelinear(
    const float* __restrict__ ctx_part, const float* __restrict__ motion,
    const float* __restrict__ pre_W, const float* __restrict__ pre_b,
    float* __restrict__ xpre) {
  int b = blockIdx.x;
  int g = threadIdx.x;
  __shared__ float cm[D + H];  // concat: motion(128) then context(256)
  float c = 0.f;
#pragma unroll
  for (int p = 0; p < TCHUNK; ++p) c += ctx_part[((size_t)p * B + b) * H + g];
  cm[D + g] = c;
  if (g < D) cm[g] = motion[b * D + g];
  __syncthreads();
  const float* wr = pre_W + (size_t)g * (D + H);
  float acc = pre_b[g];
#pragma unroll 4
  for (int j = 0; j < D + H; ++j) acc += cm[j] * wr[j];
  xpre[b * H + g] = acc;
}

// ---------------- K5b: batchnorm (over B) + relu ----
__global__ __launch_bounds__(256) void k5b_bn(
    const float* __restrict__ xpre, const float* __restrict__ gamma,
    const float* __restrict__ beta, float* __restrict__ xn) {
  int g = threadIdx.x;  // single block, 256 threads
  float mu = 0.f;
  for (int b = 0; b < B; ++b) mu += xpre[b * H + g];
  mu *= (1.f / B);
  float var = 0.f;
  for (int b = 0; b < B; ++b) {
    float d = xpre[b * H + g] - mu;
    var += d * d;
  }
  var *= (1.f / B);
  float sc = gamma[g] * rsqrtf(var + EPS);
  float bi = beta[g];
  for (int b = 0; b < B; ++b) {
    float y = (xpre[b * H + g] - mu) * sc + bi;
    xn[b * H + g] = fmaxf(y, 0.f);
  }
}

// ---------------- K6: GRU cell + output projection (fused) ----
__global__ __launch_bounds__(256) void k6_gru_out(
    const float* __restrict__ xn, const float* __restrict__ gh,
    const float* __restrict__ W_ih, const float* __restrict__ b_ih,
    const float* __restrict__ last_hidden, const float* __restrict__ out_W,
    const float* __restrict__ out_b, float* __restrict__ out_output,
    float* __restrict__ out_hidden) {
  int b = blockIdx.x;
  int g = threadIdx.x;
  __shared__ float xr[H];
  __shared__ float hn[H];
  xr[g] = xn[b * H + g];
  __syncthreads();
  float gi[3];
#pragma unroll
  for (int k = 0; k < 3; ++k) {
    int row = k * H + g;
    const float* wr = W_ih + (size_t)row * H;
    float a = b_ih[row];
#pragma unroll 4
    for (int h = 0; h < H; ++h) a += xr[h] * wr[h];
    gi[k] = a;
  }
  float hr = gh[(size_t)b * 3 * H + g];
  float hz = gh[(size_t)b * 3 * H + H + g];
  float hnn = gh[(size_t)b * 3 * H + 2 * H + g];
  float r = 1.f / (1.f + expf(-(gi[0] + hr)));
  float z = 1.f / (1.f + expf(-(gi[1] + hz)));
  float n = tanhf(gi[2] + r * hnn);
  float hprev = last_hidden[b * H + g];
  float hnew = (1.f - z) * n + z * hprev;
  out_hidden[b * H + g] = hnew;
  hn[g] = hnew;
  __syncthreads();
  if (g < O) {
    const float* wr = out_W + (size_t)g * H;
    float a = out_b[g];
#pragma unroll 4
    for (int h = 0; h < H; ++h) a += hn[h] * wr[h];
    out_output[b * O + g] = a;
  }
}

extern "C" void kernel_launch(void* const* d_in, const int* in_sizes, int n_in,
                              void* d_out, int out_size, void* d_ws,
                              size_t ws_size, hipStream_t stream) {
  (void)in_sizes; (void)n_in; (void)out_size; (void)ws_size;
  const float* motion      = (const float*)d_in[0];
  const float* last_hidden = (const float*)d_in[1];
  const float* enc         = (const float*)d_in[2];
  const float* attn_W      = (const float*)d_in[3];
  const float* attn_b      = (const float*)d_in[4];
  const float* v           = (const float*)d_in[5];
  const float* pre_W       = (const float*)d_in[6];
  const float* pre_b       = (const float*)d_in[7];
  const float* bn_g        = (const float*)d_in[8];
  const float* bn_b        = (const float*)d_in[9];
  const float* W_ih        = (const float*)d_in[10];
  const float* b_ih        = (const float*)d_in[11];
  const float* W_hh        = (const float*)d_in[12];
  const float* b_hh        = (const float*)d_in[13];
  const float* out_W       = (const float*)d_in[14];
  const float* out_b       = (const float*)d_in[15];

  float* out = (float*)d_out;
  float* out_output = out;                    // B*O
  float* out_hidden = out + B * O;            // B*H
  float* out_attn   = out + B * O + B * H;    // B*T

  float* ws = (float*)d_ws;
  float* sc = ws;                                   // B*T      = 262144
  float* cp = sc + (size_t)B * T;                   // 16*B*H   = 262144
  float* hp = cp + (size_t)TCHUNK * B * H;          // B*H      = 16384
  float* gh = hp + (size_t)B * H;                   // B*3H     = 49152
  float* xp = gh + (size_t)B * 3 * H;               // B*H      = 16384
  float* xn = xp + (size_t)B * H;                   // B*H      = 16384

  k1_hidproj_gh<<<B, 256, 0, stream>>>(last_hidden, attn_W, attn_b, W_hh, b_hh,
                                       hp, gh);
  k2_scores<<<dim3(T / TT, B), 256, 0, stream>>>(enc, attn_W, hp, v, sc);
  k3_softmax<<<B, 256, 0, stream>>>(sc, out_attn);
  k4_ctx_part<<<dim3(TCHUNK, B), 256, 0, stream>>>(enc, out_attn, cp);
  k5_prelinear<<<B, 256, 0, stream>>>(cp, motion, pre_W, pre_b, xp);
  k5b_bn<<<1, 256, 0, stream>>>(xp, bn_g, bn_b, xn);
  k6_gru_out<<<B, 256, 0, stream>>>(xn, gh, W_ih, b_ih, last_hidden, out_W,
                                    out_b, out_output, out_hidden);
}

// Round 2
// 486.994 us; speedup vs baseline: 1.9289x; 1.9289x over previous
//
#include <hip/hip_runtime.h>
#include <math.h>

#define B 64
#define T 4096
#define H 256
#define D 128
#define O 128
#define EPS 1e-5f

#define TT 64        // t-tile per block in scores kernel (4 waves x 16 rows)
#define TCHUNK 16    // t-chunks for context partials

typedef _Float16 half8 __attribute__((ext_vector_type(8)));
typedef float f32x4 __attribute__((ext_vector_type(4)));

// ---------------- K0: convert W_e (= attn_W[:, H:]) to f16, row-major [g][h] ----
__global__ __launch_bounds__(256) void k0_convW(const float* __restrict__ attn_W,
                                               _Float16* __restrict__ Wf16) {
  int idx = blockIdx.x * 256 + threadIdx.x;  // 0..65535
  int g = idx >> 8;
  int h = idx & 255;
  Wf16[idx] = (_Float16)attn_W[(size_t)g * (2 * H) + H + h];
}

// ---------------- K1: hid_proj = h_prev @ W_h^T + attn_b ; gh = h_prev @ W_hh^T + b_hh ----
__global__ __launch_bounds__(256) void k1_hidproj_gh(
    const float* __restrict__ last_hidden, const float* __restrict__ attn_W,
    const float* __restrict__ attn_b, const float* __restrict__ W_hh,
    const float* __restrict__ b_hh, float* __restrict__ hid_proj,
    float* __restrict__ gh) {
  int b = blockIdx.x;
  int g = threadIdx.x;  // 0..255
  __shared__ __align__(16) float hp[H];
  hp[g] = last_hidden[b * H + g];
  __syncthreads();
  const float4* hp4 = reinterpret_cast<const float4*>(hp);
  // hid_proj
  const float4* wr = reinterpret_cast<const float4*>(attn_W + (size_t)g * (2 * H));
  float acc = attn_b[g];
#pragma unroll 8
  for (int h4 = 0; h4 < H / 4; ++h4) {
    float4 w = wr[h4], x = hp4[h4];
    acc += w.x * x.x + w.y * x.y + w.z * x.z + w.w * x.w;
  }
  hid_proj[b * H + g] = acc;
  // gh: rows g, g+H, g+2H
#pragma unroll
  for (int k = 0; k < 3; ++k) {
    int row = k * H + g;
    const float4* whr = reinterpret_cast<const float4*>(W_hh + (size_t)row * H);
    float a2 = b_hh[row];
#pragma unroll 8
    for (int h4 = 0; h4 < H / 4; ++h4) {
      float4 w = whr[h4], x = hp4[h4];
      a2 += w.x * x.x + w.y * x.y + w.z * x.z + w.w * x.w;
    }
    gh[(size_t)b * (3 * H) + row] = a2;
  }
}

// ---------------- K2: MFMA scores[b,t] = sum_g v[g]*tanh(hid_proj[b,g] + enc[t,b,:]·W_e[g,:]) ----
// Per block: 64 t-rows x 256 g, K=256. 4 waves, each wave does 16 t-rows.
// mfma_f32_16x16x32_f16: A row = lane&15, k = (lane>>4)*8+j ; B col = lane&15,
// same k ; D col = lane&15, row = (lane>>4)*4 + reg.
__global__ __launch_bounds__(256) void k2_scores_mfma(
    const float* __restrict__ enc, const _Float16* __restrict__ Wf16,
    const float* __restrict__ hid_proj, const float* __restrict__ v,
    float* __restrict__ scores) {
  const int b = blockIdx.y;
  const int t0 = blockIdx.x * TT;
  const int tid = threadIdx.x;
  const int wave = tid >> 6;
  const int lane = tid & 63;
  const int r = lane & 15;    // fragment col / A row
  const int grp = lane >> 4;  // 0..3

  const int trow = t0 + wave * 16 + r;  // A-operand t row for this lane
  const float* aptr = enc + ((size_t)trow * B + b) * H + grp * 8;

  f32x4 acc[16];
#pragma unroll
  for (int i = 0; i < 16; ++i) acc[i] = (f32x4){0.f, 0.f, 0.f, 0.f};

#pragma unroll
  for (int kt = 0; kt < 8; ++kt) {
    const int k0 = kt * 32;
    float4 a0 = *reinterpret_cast<const float4*>(aptr + k0);
    float4 a1 = *reinterpret_cast<const float4*>(aptr + k0 + 4);
    half8 a;
    a[0] = (_Float16)a0.x; a[1] = (_Float16)a0.y;
    a[2] = (_Float16)a0.z; a[3] = (_Float16)a0.w;
    a[4] = (_Float16)a1.x; a[5] = (_Float16)a1.y;
    a[6] = (_Float16)a1.z; a[7] = (_Float16)a1.w;
    const _Float16* bbase = Wf16 + (size_t)r * H + k0 + grp * 8;
#pragma unroll
    for (int nt = 0; nt < 16; ++nt) {
      half8 bfrag = *reinterpret_cast<const half8*>(bbase + nt * 16 * H);
      acc[nt] = __builtin_amdgcn_mfma_f32_16x16x32_f16(a, bfrag, acc[nt], 0, 0, 0);
    }
  }

  // epilogue: energy -> v*tanh -> reduce over g (16 lane-cols x 16 n-tiles)
  float sum0 = 0.f, sum1 = 0.f, sum2 = 0.f, sum3 = 0.f;
#pragma unroll
  for (int nt = 0; nt < 16; ++nt) {
    int g = nt * 16 + r;
    float hpv = hid_proj[b * H + g];
    float vg = v[g];
    sum0 += vg * tanhf(acc[nt][0] + hpv);
    sum1 += vg * tanhf(acc[nt][1] + hpv);
    sum2 += vg * tanhf(acc[nt][2] + hpv);
    sum3 += vg * tanhf(acc[nt][3] + hpv);
  }
#pragma unroll
  for (int off = 1; off < 16; off <<= 1) {
    sum0 += __shfl_xor(sum0, off);
    sum1 += __shfl_xor(sum1, off);
    sum2 += __shfl_xor(sum2, off);
    sum3 += __shfl_xor(sum3, off);
  }
  if (r == 0) {
    int tbase = t0 + wave * 16 + grp * 4;
    scores[(size_t)b * T + tbase + 0] = sum0;
    scores[(size_t)b * T + tbase + 1] = sum1;
    scores[(size_t)b * T + tbase + 2] = sum2;
    scores[(size_t)b * T + tbase + 3] = sum3;
  }
}

// ---------------- K3: softmax over T per b; writes attn_weights to output ----
__global__ __launch_bounds__(256) void k3_softmax(
    const float* __restrict__ scores, float* __restrict__ attn_out) {
  int b = blockIdx.x;
  int tid = threadIdx.x;
  float vals[16];
  const float4* sp = reinterpret_cast<const float4*>(scores + (size_t)b * T);
#pragma unroll
  for (int i = 0; i < 4; ++i) {
    float4 x = sp[i * 256 + tid];
    vals[i * 4 + 0] = x.x; vals[i * 4 + 1] = x.y;
    vals[i * 4 + 2] = x.z; vals[i * 4 + 3] = x.w;
  }
  float m = -INFINITY;
#pragma unroll
  for (int i = 0; i < 16; ++i) m = fmaxf(m, vals[i]);
  for (int off = 32; off > 0; off >>= 1) m = fmaxf(m, __shfl_xor(m, off));
  __shared__ float redm[4];
  int wave = tid >> 6, lane = tid & 63;
  if (lane == 0) redm[wave] = m;
  __syncthreads();
  m = fmaxf(fmaxf(redm[0], redm[1]), fmaxf(redm[2], redm[3]));
  float s = 0.f;
#pragma unroll
  for (int i = 0; i < 16; ++i) {
    vals[i] = expf(vals[i] - m);
    s += vals[i];
  }
  for (int off = 32; off > 0; off >>= 1) s += __shfl_xor(s, off);
  __shared__ float reds[4];
  if (lane == 0) reds[wave] = s;
  __syncthreads();
  s = reds[0] + reds[1] + reds[2] + reds[3];
  float inv = 1.f / s;
  float4* op = reinterpret_cast<float4*>(attn_out + (size_t)b * T);
#pragma unroll
  for (int i = 0; i < 4; ++i) {
    float4 x;
    x.x = vals[i * 4 + 0] * inv; x.y = vals[i * 4 + 1] * inv;
    x.z = vals[i * 4 + 2] * inv; x.w = vals[i * 4 + 3] * inv;
    op[i * 256 + tid] = x;
  }
}

// ---------------- K4: context partials over t-chunks ----
__global__ __launch_bounds__(256) void k4_ctx_part(
    const float* __restrict__ enc, const float* __restrict__ attn_w,
    float* __restrict__ ctx_part) {
  int chunk = blockIdx.x;
  int b = blockIdx.y;
  int tid = threadIdx.x;
  int h4 = tid & 63;
  int tsub = tid >> 6;  // 0..3
  int tstart = chunk * (T / TCHUNK);
  float4 acc = {0.f, 0.f, 0.f, 0.f};
  const float* wrow = attn_w + (size_t)b * T;
  for (int t = tstart + tsub; t < tstart + T / TCHUNK; t += 4) {
    float w = wrow[t];
    float4 e = *reinterpret_cast<const float4*>(
        enc + ((size_t)t * B + b) * H + h4 * 4);
    acc.x += w * e.x; acc.y += w * e.y; acc.z += w * e.z; acc.w += w * e.w;
  }
  __shared__ float4 red[4][64];
  red[tsub][h4] = acc;
  __syncthreads();
  if (tid < 64) {
    float4 a = red[0][tid], b2 = red[1][tid], c = red[2][tid], d2 = red[3][tid];
    float4 r;
    r.x = a.x + b2.x + c.x + d2.x;
    r.y = a.y + b2.y + c.y + d2.y;
    r.z = a.z + b2.z + c.z + d2.z;
    r.w = a.w + b2.w + c.w + d2.w;
    *reinterpret_cast<float4*>(ctx_part + ((size_t)chunk * B + b) * H + tid * 4) = r;
  }
}

// ---------------- K5: x = concat(motion, context) @ pre_W^T + pre_b ----
__global__ __launch_bounds__(256) void k5_prelinear(
    const float* __restrict__ ctx_part, const float* __restrict__ motion,
    const float* __restrict__ pre_W, const float* __restrict__ pre_b,
    float* __restrict__ xpre) {
  int b = blockIdx.x;
  int g = threadIdx.x;
  __shared__ __align__(16) float cm[D + H];  // concat: motion(128) then context(256)
  float c = 0.f;
#pragma unroll
  for (int p = 0; p < TCHUNK; ++p) c += ctx_part[((size_t)p * B + b) * H + g];
  cm[D + g] = c;
  if (g < D) cm[g] = motion[b * D + g];
  __syncthreads();
  const float4* cm4 = reinterpret_cast<const float4*>(cm);
  const float4* wr = reinterpret_cast<const float4*>(pre_W + (size_t)g * (D + H));
  float acc = pre_b[g];
#pragma unroll 8
  for (int j = 0; j < (D + H) / 4; ++j) {
    float4 w = wr[j], x = cm4[j];
    acc += w.x * x.x + w.y * x.y + w.z * x.z + w.w * x.w;
  }
  xpre[b * H + g] = acc;
}

// ---------------- K5b: batchnorm (over B) + relu ----
__global__ __launch_bounds__(256) void k5b_bn(
    const float* __restrict__ xpre, const float* __restrict__ gamma,
    const float* __restrict__ beta, float* __restrict__ xn) {
  int g = threadIdx.x;  // single block, 256 threads
  float mu = 0.f;
  for (int b = 0; b < B; ++b) mu += xpre[b * H + g];
  mu *= (1.f / B);
  float var = 0.f;
  for (int b = 0; b < B; ++b) {
    float d = xpre[b * H + g] - mu;
    var += d * d;
  }
  var *= (1.f / B);
  float sc = gamma[g] * rsqrtf(var + EPS);
  float bi = beta[g];
  for (int b = 0; b < B; ++b) {
    float y = (xpre[b * H + g] - mu) * sc + bi;
    xn[b * H + g] = fmaxf(y, 0.f);
  }
}

// ---------------- K6: GRU cell + output projection (fused) ----
__global__ __launch_bounds__(256) void k6_gru_out(
    const float* __restrict__ xn, const float* __restrict__ gh,
    const float* __restrict__ W_ih, const float* __restrict__ b_ih,
    const float* __restrict__ last_hidden, const float* __restrict__ out_W,
    const float* __restrict__ out_b, float* __restrict__ out_output,
    float* __restrict__ out_hidden) {
  int b = blockIdx.x;
  int g = threadIdx.x;
  __shared__ __align__(16) float xr[H];
  __shared__ __align__(16) float hn[H];
  xr[g] = xn[b * H + g];
  __syncthreads();
  const float4* xr4 = reinterpret_cast<const float4*>(xr);
  float gi[3];
#pragma unroll
  for (int k = 0; k < 3; ++k) {
    int row = k * H + g;
    const float4* wr = reinterpret_cast<const float4*>(W_ih + (size_t)row * H);
    float a = b_ih[row];
#pragma unroll 8
    for (int h4 = 0; h4 < H / 4; ++h4) {
      float4 w = wr[h4], x = xr4[h4];
      a += w.x * x.x + w.y * x.y + w.z * x.z + w.w * x.w;
    }
    gi[k] = a;
  }
  float hr = gh[(size_t)b * 3 * H + g];
  float hz = gh[(size_t)b * 3 * H + H + g];
  float hnn = gh[(size_t)b * 3 * H + 2 * H + g];
  float r = 1.f / (1.f + expf(-(gi[0] + hr)));
  float z = 1.f / (1.f + expf(-(gi[1] + hz)));
  float n = tanhf(gi[2] + r * hnn);
  float hprev = last_hidden[b * H + g];
  float hnew = (1.f - z) * n + z * hprev;
  out_hidden[b * H + g] = hnew;
  hn[g] = hnew;
  __syncthreads();
  if (g < O) {
    const float4* hn4 = reinterpret_cast<const float4*>(hn);
    const float4* wr = reinterpret_cast<const float4*>(out_W + (size_t)g * H);
    float a = out_b[g];
#pragma unroll 8
    for (int h4 = 0; h4 < H / 4; ++h4) {
      float4 w = wr[h4], x = hn4[h4];
      a += w.x * x.x + w.y * x.y + w.z * x.z + w.w * x.w;
    }
    out_output[b * O + g] = a;
  }
}

extern "C" void kernel_launch(void* const* d_in, const int* in_sizes, int n_in,
                              void* d_out, int out_size, void* d_ws,
                              size_t ws_size, hipStream_t stream) {
  (void)in_sizes; (void)n_in; (void)out_size; (void)ws_size;
  const float* motion      = (const float*)d_in[0];
  const float* last_hidden = (const float*)d_in[1];
  const float* enc         = (const float*)d_in[2];
  const float* attn_W      = (const float*)d_in[3];
  const float* attn_b      = (const float*)d_in[4];
  const float* v           = (const float*)d_in[5];
  const float* pre_W       = (const float*)d_in[6];
  const float* pre_b       = (const float*)d_in[7];
  const float* bn_g        = (const float*)d_in[8];
  const float* bn_b        = (const float*)d_in[9];
  const float* W_ih        = (const float*)d_in[10];
  const float* b_ih        = (const float*)d_in[11];
  const float* W_hh        = (const float*)d_in[12];
  const float* b_hh        = (const float*)d_in[13];
  const float* out_W       = (const float*)d_in[14];
  const float* out_b       = (const float*)d_in[15];

  float* out = (float*)d_out;
  float* out_output = out;                    // B*O
  float* out_hidden = out + B * O;            // B*H
  float* out_attn   = out + B * O + B * H;    // B*T

  float* ws = (float*)d_ws;
  float* sc = ws;                                   // B*T      = 262144
  float* cp = sc + (size_t)B * T;                   // 16*B*H   = 262144
  float* hp = cp + (size_t)TCHUNK * B * H;          // B*H      = 16384
  float* gh = hp + (size_t)B * H;                   // B*3H     = 49152
  float* xp = gh + (size_t)B * 3 * H;               // B*H      = 16384
  float* xn = xp + (size_t)B * H;                   // B*H      = 16384
  _Float16* Wf16 = (_Float16*)(xn + (size_t)B * H); // H*H f16  = 128KB

  k0_convW<<<256, 256, 0, stream>>>(attn_W, Wf16);
  k1_hidproj_gh<<<B, 256, 0, stream>>>(last_hidden, attn_W, attn_b, W_hh, b_hh,
                                       hp, gh);
  k2_scores_mfma<<<dim3(T / TT, B), 256, 0, stream>>>(enc, Wf16, hp, v, sc);
  k3_softmax<<<B, 256, 0, stream>>>(sc, out_attn);
  k4_ctx_part<<<dim3(TCHUNK, B), 256, 0, stream>>>(enc, out_attn, cp);
  k5_prelinear<<<B, 256, 0, stream>>>(cp, motion, pre_W, pre_b, xp);
  k5b_bn<<<1, 256, 0, stream>>>(xp, bn_g, bn_b, xn);
  k6_gru_out<<<B, 256, 0, stream>>>(xn, gh, W_ih, b_ih, last_hidden, out_W,
                                    out_b, out_output, out_hidden);
}

// Round 3
// 473.673 us; speedup vs baseline: 1.9831x; 1.0281x over previous
//
#include <hip/hip_runtime.h>
#include <math.h>

#define B 64
#define T 4096
#define H 256
#define D 128
#define O 128
#define EPS 1e-5f

#define TT 64        // t-tile per block in scores kernel (4 waves x 16 rows)
#define TCHUNK 16    // t-chunks for context partials

typedef _Float16 half8 __attribute__((ext_vector_type(8)));
typedef float f32x4 __attribute__((ext_vector_type(4)));

// ---------------- K0: permute W_e (= attn_W[:, H:]) into f16 MFMA-fragment order ----
// Bperm[(((nt*8)+kt)*64 + lane)*8 + j] = W_e[nt*16+(lane&15)][kt*32+(lane>>4)*8+j]
// so a wave's B-fragment load for (kt,nt) is one contiguous 1KB segment.
__global__ __launch_bounds__(256) void k0_permW(const float* __restrict__ attn_W,
                                               _Float16* __restrict__ Bperm) {
  int idx = blockIdx.x * 256 + threadIdx.x;  // 0..65535
  int j = idx & 7;
  int l = (idx >> 3) & 63;
  int kt = (idx >> 9) & 7;
  int nt = idx >> 12;
  int g = nt * 16 + (l & 15);
  int k = kt * 32 + ((l >> 4) << 3) + j;
  Bperm[idx] = (_Float16)attn_W[(size_t)g * (2 * H) + H + k];
}

// ---------------- K1: hid_proj = h_prev @ W_h^T + attn_b ; gh = h_prev @ W_hh^T + b_hh ----
__global__ __launch_bounds__(256) void k1_hidproj_gh(
    const float* __restrict__ last_hidden, const float* __restrict__ attn_W,
    const float* __restrict__ attn_b, const float* __restrict__ W_hh,
    const float* __restrict__ b_hh, float* __restrict__ hid_proj,
    float* __restrict__ gh) {
  int b = blockIdx.x;
  int g = threadIdx.x;  // 0..255
  __shared__ __align__(16) float hp[H];
  hp[g] = last_hidden[b * H + g];
  __syncthreads();
  const float4* hp4 = reinterpret_cast<const float4*>(hp);
  const float4* wr = reinterpret_cast<const float4*>(attn_W + (size_t)g * (2 * H));
  float acc = attn_b[g];
#pragma unroll 8
  for (int h4 = 0; h4 < H / 4; ++h4) {
    float4 w = wr[h4], x = hp4[h4];
    acc += w.x * x.x + w.y * x.y + w.z * x.z + w.w * x.w;
  }
  hid_proj[b * H + g] = acc;
#pragma unroll
  for (int k = 0; k < 3; ++k) {
    int row = k * H + g;
    const float4* whr = reinterpret_cast<const float4*>(W_hh + (size_t)row * H);
    float a2 = b_hh[row];
#pragma unroll 8
    for (int h4 = 0; h4 < H / 4; ++h4) {
      float4 w = whr[h4], x = hp4[h4];
      a2 += w.x * x.x + w.y * x.y + w.z * x.z + w.w * x.w;
    }
    gh[(size_t)b * (3 * H) + row] = a2;
  }
}

// ---------------- K2: MFMA scores. Per block: 64 t-rows x 256 g, K=256. ----
// 4 waves, each wave 16 t-rows. B-fragments pre-permuted (coalesced 1KB loads).
__global__ __launch_bounds__(256) void k2_scores_mfma(
    const float* __restrict__ enc, const _Float16* __restrict__ Bperm,
    const float* __restrict__ hid_proj, const float* __restrict__ v,
    float* __restrict__ scores) {
  const int b = blockIdx.y;
  const int t0 = blockIdx.x * TT;
  const int tid = threadIdx.x;
  const int wave = tid >> 6;
  const int lane = tid & 63;
  const int r = lane & 15;    // fragment col / A row
  const int grp = lane >> 4;  // 0..3

  const int trow = t0 + wave * 16 + r;  // A-operand t row for this lane
  const float* aptr = enc + ((size_t)trow * B + b) * H + grp * 8;
  const half8* bp = reinterpret_cast<const half8*>(Bperm);

  f32x4 acc[16];
#pragma unroll
  for (int i = 0; i < 16; ++i) acc[i] = (f32x4){0.f, 0.f, 0.f, 0.f};

  // A-frag load (f32 -> f16 convert in-register)
  auto loadA = [&](int kt) -> half8 {
    const int k0 = kt * 32;
    float4 a0 = *reinterpret_cast<const float4*>(aptr + k0);
    float4 a1 = *reinterpret_cast<const float4*>(aptr + k0 + 4);
    half8 a;
    a[0] = (_Float16)a0.x; a[1] = (_Float16)a0.y;
    a[2] = (_Float16)a0.z; a[3] = (_Float16)a0.w;
    a[4] = (_Float16)a1.x; a[5] = (_Float16)a1.y;
    a[6] = (_Float16)a1.z; a[7] = (_Float16)a1.w;
    return a;
  };

  half8 a_cur = loadA(0);
#pragma unroll
  for (int kt = 0; kt < 8; ++kt) {
    half8 a_next = (kt < 7) ? loadA(kt + 1) : a_cur;
#pragma unroll
    for (int nt = 0; nt < 16; ++nt) {
      half8 bfrag = bp[(nt * 8 + kt) * 64 + lane];
      acc[nt] = __builtin_amdgcn_mfma_f32_16x16x32_f16(a_cur, bfrag, acc[nt], 0, 0, 0);
    }
    a_cur = a_next;
  }

  // epilogue: energy -> v*tanh -> reduce over g (16 lane-cols x 16 n-tiles)
  float sum0 = 0.f, sum1 = 0.f, sum2 = 0.f, sum3 = 0.f;
#pragma unroll
  for (int nt = 0; nt < 16; ++nt) {
    int g = nt * 16 + r;
    float hpv = hid_proj[b * H + g];
    float vg = v[g];
    sum0 += vg * tanhf(acc[nt][0] + hpv);
    sum1 += vg * tanhf(acc[nt][1] + hpv);
    sum2 += vg * tanhf(acc[nt][2] + hpv);
    sum3 += vg * tanhf(acc[nt][3] + hpv);
  }
#pragma unroll
  for (int off = 1; off < 16; off <<= 1) {
    sum0 += __shfl_xor(sum0, off);
    sum1 += __shfl_xor(sum1, off);
    sum2 += __shfl_xor(sum2, off);
    sum3 += __shfl_xor(sum3, off);
  }
  if (r == 0) {
    int tbase = t0 + wave * 16 + grp * 4;
    scores[(size_t)b * T + tbase + 0] = sum0;
    scores[(size_t)b * T + tbase + 1] = sum1;
    scores[(size_t)b * T + tbase + 2] = sum2;
    scores[(size_t)b * T + tbase + 3] = sum3;
  }
}

// ---------------- K3: softmax over T per b; writes attn_weights to output ----
__global__ __launch_bounds__(256) void k3_softmax(
    const float* __restrict__ scores, float* __restrict__ attn_out) {
  int b = blockIdx.x;
  int tid = threadIdx.x;
  float vals[16];
  const float4* sp = reinterpret_cast<const float4*>(scores + (size_t)b * T);
#pragma unroll
  for (int i = 0; i < 4; ++i) {
    float4 x = sp[i * 256 + tid];
    vals[i * 4 + 0] = x.x; vals[i * 4 + 1] = x.y;
    vals[i * 4 + 2] = x.z; vals[i * 4 + 3] = x.w;
  }
  float m = -INFINITY;
#pragma unroll
  for (int i = 0; i < 16; ++i) m = fmaxf(m, vals[i]);
  for (int off = 32; off > 0; off >>= 1) m = fmaxf(m, __shfl_xor(m, off));
  __shared__ float redm[4];
  int wave = tid >> 6, lane = tid & 63;
  if (lane == 0) redm[wave] = m;
  __syncthreads();
  m = fmaxf(fmaxf(redm[0], redm[1]), fmaxf(redm[2], redm[3]));
  float s = 0.f;
#pragma unroll
  for (int i = 0; i < 16; ++i) {
    vals[i] = expf(vals[i] - m);
    s += vals[i];
  }
  for (int off = 32; off > 0; off >>= 1) s += __shfl_xor(s, off);
  __shared__ float reds[4];
  if (lane == 0) reds[wave] = s;
  __syncthreads();
  s = reds[0] + reds[1] + reds[2] + reds[3];
  float inv = 1.f / s;
  float4* op = reinterpret_cast<float4*>(attn_out + (size_t)b * T);
#pragma unroll
  for (int i = 0; i < 4; ++i) {
    float4 x;
    x.x = vals[i * 4 + 0] * inv; x.y = vals[i * 4 + 1] * inv;
    x.z = vals[i * 4 + 2] * inv; x.w = vals[i * 4 + 3] * inv;
    op[i * 256 + tid] = x;
  }
}

// ---------------- K4: context partials over t-chunks ----
__global__ __launch_bounds__(256) void k4_ctx_part(
    const float* __restrict__ enc, const float* __restrict__ attn_w,
    float* __restrict__ ctx_part) {
  int chunk = blockIdx.x;
  int b = blockIdx.y;
  int tid = threadIdx.x;
  int h4 = tid & 63;
  int tsub = tid >> 6;  // 0..3
  int tstart = chunk * (T / TCHUNK);
  float4 acc = {0.f, 0.f, 0.f, 0.f};
  const float* wrow = attn_w + (size_t)b * T;
  for (int t = tstart + tsub; t < tstart + T / TCHUNK; t += 4) {
    float w = wrow[t];
    float4 e = *reinterpret_cast<const float4*>(
        enc + ((size_t)t * B + b) * H + h4 * 4);
    acc.x += w * e.x; acc.y += w * e.y; acc.z += w * e.z; acc.w += w * e.w;
  }
  __shared__ float4 red[4][64];
  red[tsub][h4] = acc;
  __syncthreads();
  if (tid < 64) {
    float4 a = red[0][tid], b2 = red[1][tid], c = red[2][tid], d2 = red[3][tid];
    float4 r;
    r.x = a.x + b2.x + c.x + d2.x;
    r.y = a.y + b2.y + c.y + d2.y;
    r.z = a.z + b2.z + c.z + d2.z;
    r.w = a.w + b2.w + c.w + d2.w;
    *reinterpret_cast<float4*>(ctx_part + ((size_t)chunk * B + b) * H + tid * 4) = r;
  }
}

// ---------------- K5: x = concat(motion, context) @ pre_W^T + pre_b ----
__global__ __launch_bounds__(256) void k5_prelinear(
    const float* __restrict__ ctx_part, const float* __restrict__ motion,
    const float* __restrict__ pre_W, const float* __restrict__ pre_b,
    float* __restrict__ xpre) {
  int b = blockIdx.x;
  int g = threadIdx.x;
  __shared__ __align__(16) float cm[D + H];
  float c = 0.f;
#pragma unroll
  for (int p = 0; p < TCHUNK; ++p) c += ctx_part[((size_t)p * B + b) * H + g];
  cm[D + g] = c;
  if (g < D) cm[g] = motion[b * D + g];
  __syncthreads();
  const float4* cm4 = reinterpret_cast<const float4*>(cm);
  const float4* wr = reinterpret_cast<const float4*>(pre_W + (size_t)g * (D + H));
  float acc = pre_b[g];
#pragma unroll 8
  for (int j = 0; j < (D + H) / 4; ++j) {
    float4 w = wr[j], x = cm4[j];
    acc += w.x * x.x + w.y * x.y + w.z * x.z + w.w * x.w;
  }
  xpre[b * H + g] = acc;
}

// ---------------- K5b: batchnorm (over B) + relu ----
__global__ __launch_bounds__(256) void k5b_bn(
    const float* __restrict__ xpre, const float* __restrict__ gamma,
    const float* __restrict__ beta, float* __restrict__ xn) {
  int g = threadIdx.x;
  float mu = 0.f;
  for (int b = 0; b < B; ++b) mu += xpre[b * H + g];
  mu *= (1.f / B);
  float var = 0.f;
  for (int b = 0; b < B; ++b) {
    float d = xpre[b * H + g] - mu;
    var += d * d;
  }
  var *= (1.f / B);
  float sc = gamma[g] * rsqrtf(var + EPS);
  float bi = beta[g];
  for (int b = 0; b < B; ++b) {
    float y = (xpre[b * H + g] - mu) * sc + bi;
    xn[b * H + g] = fmaxf(y, 0.f);
  }
}

// ---------------- K6: GRU cell + output projection (fused) ----
__global__ __launch_bounds__(256) void k6_gru_out(
    const float* __restrict__ xn, const float* __restrict__ gh,
    const float* __restrict__ W_ih, const float* __restrict__ b_ih,
    const float* __restrict__ last_hidden, const float* __restrict__ out_W,
    const float* __restrict__ out_b, float* __restrict__ out_output,
    float* __restrict__ out_hidden) {
  int b = blockIdx.x;
  int g = threadIdx.x;
  __shared__ __align__(16) float xr[H];
  __shared__ __align__(16) float hn[H];
  xr[g] = xn[b * H + g];
  __syncthreads();
  const float4* xr4 = reinterpret_cast<const float4*>(xr);
  float gi[3];
#pragma unroll
  for (int k = 0; k < 3; ++k) {
    int row = k * H + g;
    const float4* wr = reinterpret_cast<const float4*>(W_ih + (size_t)row * H);
    float a = b_ih[row];
#pragma unroll 8
    for (int h4 = 0; h4 < H / 4; ++h4) {
      float4 w = wr[h4], x = xr4[h4];
      a += w.x * x.x + w.y * x.y + w.z * x.z + w.w * x.w;
    }
    gi[k] = a;
  }
  float hr = gh[(size_t)b * 3 * H + g];
  float hz = gh[(size_t)b * 3 * H + H + g];
  float hnn = gh[(size_t)b * 3 * H + 2 * H + g];
  float r = 1.f / (1.f + expf(-(gi[0] + hr)));
  float z = 1.f / (1.f + expf(-(gi[1] + hz)));
  float n = tanhf(gi[2] + r * hnn);
  float hprev = last_hidden[b * H + g];
  float hnew = (1.f - z) * n + z * hprev;
  out_hidden[b * H + g] = hnew;
  hn[g] = hnew;
  __syncthreads();
  if (g < O) {
    const float4* hn4 = reinterpret_cast<const float4*>(hn);
    const float4* wr = reinterpret_cast<const float4*>(out_W + (size_t)g * H);
    float a = out_b[g];
#pragma unroll 8
    for (int h4 = 0; h4 < H / 4; ++h4) {
      float4 w = wr[h4], x = hn4[h4];
      a += w.x * x.x + w.y * x.y + w.z * x.z + w.w * x.w;
    }
    out_output[b * O + g] = a;
  }
}

extern "C" void kernel_launch(void* const* d_in, const int* in_sizes, int n_in,
                              void* d_out, int out_size, void* d_ws,
                              size_t ws_size, hipStream_t stream) {
  (void)in_sizes; (void)n_in; (void)out_size; (void)ws_size;
  const float* motion      = (const float*)d_in[0];
  const float* last_hidden = (const float*)d_in[1];
  const float* enc         = (const float*)d_in[2];
  const float* attn_W      = (const float*)d_in[3];
  const float* attn_b      = (const float*)d_in[4];
  const float* v           = (const float*)d_in[5];
  const float* pre_W       = (const float*)d_in[6];
  const float* pre_b       = (const float*)d_in[7];
  const float* bn_g        = (const float*)d_in[8];
  const float* bn_b        = (const float*)d_in[9];
  const float* W_ih        = (const float*)d_in[10];
  const float* b_ih        = (const float*)d_in[11];
  const float* W_hh        = (const float*)d_in[12];
  const float* b_hh        = (const float*)d_in[13];
  const float* out_W       = (const float*)d_in[14];
  const float* out_b       = (const float*)d_in[15];

  float* out = (float*)d_out;
  float* out_output = out;                    // B*O
  float* out_hidden = out + B * O;            // B*H
  float* out_attn   = out + B * O + B * H;    // B*T

  float* ws = (float*)d_ws;
  float* sc = ws;                                   // B*T      = 262144
  float* cp = sc + (size_t)B * T;                   // 16*B*H   = 262144
  float* hp = cp + (size_t)TCHUNK * B * H;          // B*H      = 16384
  float* gh = hp + (size_t)B * H;                   // B*3H     = 49152
  float* xp = gh + (size_t)B * 3 * H;               // B*H      = 16384
  float* xn = xp + (size_t)B * H;                   // B*H      = 16384
  _Float16* Bperm = (_Float16*)(xn + (size_t)B * H); // H*H f16 = 128KB

  k0_permW<<<256, 256, 0, stream>>>(attn_W, Bperm);
  k1_hidproj_gh<<<B, 256, 0, stream>>>(last_hidden, attn_W, attn_b, W_hh, b_hh,
                                       hp, gh);
  k2_scores_mfma<<<dim3(T / TT, B), 256, 0, stream>>>(enc, Bperm, hp, v, sc);
  k3_softmax<<<B, 256, 0, stream>>>(sc, out_attn);
  k4_ctx_part<<<dim3(TCHUNK, B), 256, 0, stream>>>(enc, out_attn, cp);
  k5_prelinear<<<B, 256, 0, stream>>>(cp, motion, pre_W, pre_b, xp);
  k5b_bn<<<1, 256, 0, stream>>>(xp, bn_g, bn_b, xn);
  k6_gru_out<<<B, 256, 0, stream>>>(xn, gh, W_ih, b_ih, last_hidden, out_W,
                                    out_b, out_output, out_hidden);
}

// Round 5
// 259.806 us; speedup vs baseline: 3.6156x; 1.8232x over previous
//
#include <hip/hip_runtime.h>
#include <math.h>

#define B 64
#define T 4096
#define H 256
#define D 128
#define O 128
#define EPS 1e-5f

#define TT 64        // t-tile per block in scores kernel (4 waves x 16 rows)
#define TCHUNK 16    // t-chunks for context partials

typedef _Float16 half8 __attribute__((ext_vector_type(8)));
typedef float f32x4 __attribute__((ext_vector_type(4)));

__device__ __forceinline__ float tanh_fast(float x) {
  // 1 - 2/(e^{2x}+1): exp overflow -> 1, exp->0 -> -1 (no inf/inf NaN)
  return 1.f - 2.f / (__expf(2.f * x) + 1.f);
}

// ---------------- K0: permute W_e (= attn_W[:, H:]) into f16 MFMA-fragment order ----
// Bperm[(((nt*8)+kt)*64 + lane)*8 + j] = W_e[nt*16+(lane&15)][kt*32+(lane>>4)*8+j]
__global__ __launch_bounds__(256) void k0_permW(const float* __restrict__ attn_W,
                                               _Float16* __restrict__ Bperm) {
  int idx = blockIdx.x * 256 + threadIdx.x;  // 0..65535
  int j = idx & 7;
  int l = (idx >> 3) & 63;
  int kt = (idx >> 9) & 7;
  int nt = idx >> 12;
  int g = nt * 16 + (l & 15);
  int k = kt * 32 + ((l >> 4) << 3) + j;
  Bperm[idx] = (_Float16)attn_W[(size_t)g * (2 * H) + H + k];
}

// ---------------- K1: hid_proj = h_prev @ W_h^T + attn_b ; gh = h_prev @ W_hh^T + b_hh ----
__global__ __launch_bounds__(256) void k1_hidproj_gh(
    const float* __restrict__ last_hidden, const float* __restrict__ attn_W,
    const float* __restrict__ attn_b, const float* __restrict__ W_hh,
    const float* __restrict__ b_hh, float* __restrict__ hid_proj,
    float* __restrict__ gh) {
  int b = blockIdx.x;
  int g = threadIdx.x;  // 0..255
  __shared__ __align__(16) float hp[H];
  hp[g] = last_hidden[b * H + g];
  __syncthreads();
  const float4* hp4 = reinterpret_cast<const float4*>(hp);
  const float4* wr = reinterpret_cast<const float4*>(attn_W + (size_t)g * (2 * H));
  float acc = attn_b[g];
#pragma unroll 8
  for (int h4 = 0; h4 < H / 4; ++h4) {
    float4 w = wr[h4], x = hp4[h4];
    acc += w.x * x.x + w.y * x.y + w.z * x.z + w.w * x.w;
  }
  hid_proj[b * H + g] = acc;
#pragma unroll
  for (int k = 0; k < 3; ++k) {
    int row = k * H + g;
    const float4* whr = reinterpret_cast<const float4*>(W_hh + (size_t)row * H);
    float a2 = b_hh[row];
#pragma unroll 8
    for (int h4 = 0; h4 < H / 4; ++h4) {
      float4 w = whr[h4], x = hp4[h4];
      a2 += w.x * x.x + w.y * x.y + w.z * x.z + w.w * x.w;
    }
    gh[(size_t)b * (3 * H) + row] = a2;
  }
}

// ---------------- K2: MFMA scores. Per block: 64 t-rows x 256 g, K=256. ----
// 4 waves x 16 t-rows. All A-loads hoisted (16 in flight); B ping-pong
// double-buffered 16 frags deep (16 L2 loads in flight under MFMA).
__global__ __launch_bounds__(256, 2) void k2_scores_mfma(
    const float* __restrict__ enc, const _Float16* __restrict__ Bperm,
    const float* __restrict__ hid_proj, const float* __restrict__ v,
    float* __restrict__ scores) {
  const int b = blockIdx.y;
  const int t0 = blockIdx.x * TT;
  const int tid = threadIdx.x;
  const int wave = tid >> 6;
  const int lane = tid & 63;
  const int r = lane & 15;    // fragment col / A row
  const int grp = lane >> 4;  // 0..3

  const int trow = t0 + wave * 16 + r;  // A-operand t row for this lane
  const float* aptr = enc + ((size_t)trow * B + b) * H + grp * 8;
  const half8* bp = reinterpret_cast<const half8*>(Bperm);

  // ---- issue ALL 16 A-loads (independent, deep in flight) ----
  float4 af0[8], af1[8];
#pragma unroll
  for (int kt = 0; kt < 8; ++kt) {
    af0[kt] = *reinterpret_cast<const float4*>(aptr + kt * 32);
    af1[kt] = *reinterpret_cast<const float4*>(aptr + kt * 32 + 4);
  }

  // ---- issue B-loads for kt=0 ----
  half8 bb[2][16];
#pragma unroll
  for (int nt = 0; nt < 16; ++nt) bb[0][nt] = bp[(nt * 8 + 0) * 64 + lane];

  // ---- convert A to f16 (waits on A-loads; B0 still in flight) ----
  half8 ah[8];
#pragma unroll
  for (int kt = 0; kt < 8; ++kt) {
    float4 a0 = af0[kt], a1 = af1[kt];
    half8 a;
    a[0] = (_Float16)a0.x; a[1] = (_Float16)a0.y;
    a[2] = (_Float16)a0.z; a[3] = (_Float16)a0.w;
    a[4] = (_Float16)a1.x; a[5] = (_Float16)a1.y;
    a[6] = (_Float16)a1.z; a[7] = (_Float16)a1.w;
    ah[kt] = a;
  }

  f32x4 acc[16];
#pragma unroll
  for (int i = 0; i < 16; ++i) acc[i] = (f32x4){0.f, 0.f, 0.f, 0.f};

#pragma unroll
  for (int kt = 0; kt < 8; ++kt) {
    const int cur = kt & 1;
    // prefetch next kt's 16 B-frags while this kt's MFMAs run
    if (kt < 7) {
#pragma unroll
      for (int nt = 0; nt < 16; ++nt)
        bb[cur ^ 1][nt] = bp[(nt * 8 + kt + 1) * 64 + lane];
    }
#pragma unroll
    for (int nt = 0; nt < 16; ++nt)
      acc[nt] = __builtin_amdgcn_mfma_f32_16x16x32_f16(ah[kt], bb[cur][nt],
                                                       acc[nt], 0, 0, 0);
  }

  // epilogue: energy -> v*tanh -> reduce over g (16 lane-cols x 16 n-tiles)
  float sum0 = 0.f, sum1 = 0.f, sum2 = 0.f, sum3 = 0.f;
#pragma unroll
  for (int nt = 0; nt < 16; ++nt) {
    int g = nt * 16 + r;
    float hpv = hid_proj[b * H + g];
    float vg = v[g];
    sum0 += vg * tanh_fast(acc[nt][0] + hpv);
    sum1 += vg * tanh_fast(acc[nt][1] + hpv);
    sum2 += vg * tanh_fast(acc[nt][2] + hpv);
    sum3 += vg * tanh_fast(acc[nt][3] + hpv);
  }
#pragma unroll
  for (int off = 1; off < 16; off <<= 1) {
    sum0 += __shfl_xor(sum0, off);
    sum1 += __shfl_xor(sum1, off);
    sum2 += __shfl_xor(sum2, off);
    sum3 += __shfl_xor(sum3, off);
  }
  if (r == 0) {
    int tbase = t0 + wave * 16 + grp * 4;
    scores[(size_t)b * T + tbase + 0] = sum0;
    scores[(size_t)b * T + tbase + 1] = sum1;
    scores[(size_t)b * T + tbase + 2] = sum2;
    scores[(size_t)b * T + tbase + 3] = sum3;
  }
}

// ---------------- K3: softmax over T per b; writes attn_weights to output ----
__global__ __launch_bounds__(256) void k3_softmax(
    const float* __restrict__ scores, float* __restrict__ attn_out) {
  int b = blockIdx.x;
  int tid = threadIdx.x;
  float vals[16];
  const float4* sp = reinterpret_cast<const float4*>(scores + (size_t)b * T);
#pragma unroll
  for (int i = 0; i < 4; ++i) {
    float4 x = sp[i * 256 + tid];
    vals[i * 4 + 0] = x.x; vals[i * 4 + 1] = x.y;
    vals[i * 4 + 2] = x.z; vals[i * 4 + 3] = x.w;
  }
  float m = -INFINITY;
#pragma unroll
  for (int i = 0; i < 16; ++i) m = fmaxf(m, vals[i]);
  for (int off = 32; off > 0; off >>= 1) m = fmaxf(m, __shfl_xor(m, off));
  __shared__ float redm[4];
  int wave = tid >> 6, lane = tid & 63;
  if (lane == 0) redm[wave] = m;
  __syncthreads();
  m = fmaxf(fmaxf(redm[0], redm[1]), fmaxf(redm[2], redm[3]));
  float s = 0.f;
#pragma unroll
  for (int i = 0; i < 16; ++i) {
    vals[i] = expf(vals[i] - m);
    s += vals[i];
  }
  for (int off = 32; off > 0; off >>= 1) s += __shfl_xor(s, off);
  __shared__ float reds[4];
  if (lane == 0) reds[wave] = s;
  __syncthreads();
  s = reds[0] + reds[1] + reds[2] + reds[3];
  float inv = 1.f / s;
  float4* op = reinterpret_cast<float4*>(attn_out + (size_t)b * T);
#pragma unroll
  for (int i = 0; i < 4; ++i) {
    float4 x;
    x.x = vals[i * 4 + 0] * inv; x.y = vals[i * 4 + 1] * inv;
    x.z = vals[i * 4 + 2] * inv; x.w = vals[i * 4 + 3] * inv;
    op[i * 256 + tid] = x;
  }
}

// ---------------- K4: context partials over t-chunks ----
__global__ __launch_bounds__(256) void k4_ctx_part(
    const float* __restrict__ enc, const float* __restrict__ attn_w,
    float* __restrict__ ctx_part) {
  int chunk = blockIdx.x;
  int b = blockIdx.y;
  int tid = threadIdx.x;
  int h4 = tid & 63;
  int tsub = tid >> 6;  // 0..3
  int tstart = chunk * (T / TCHUNK);
  float4 acc = {0.f, 0.f, 0.f, 0.f};
  const float* wrow = attn_w + (size_t)b * T;
  for (int t = tstart + tsub; t < tstart + T / TCHUNK; t += 4) {
    float w = wrow[t];
    float4 e = *reinterpret_cast<const float4*>(
        enc + ((size_t)t * B + b) * H + h4 * 4);
    acc.x += w * e.x; acc.y += w * e.y; acc.z += w * e.z; acc.w += w * e.w;
  }
  __shared__ float4 red[4][64];
  red[tsub][h4] = acc;
  __syncthreads();
  if (tid < 64) {
    float4 a = red[0][tid], b2 = red[1][tid], c = red[2][tid], d2 = red[3][tid];
    float4 r;
    r.x = a.x + b2.x + c.x + d2.x;
    r.y = a.y + b2.y + c.y + d2.y;
    r.z = a.z + b2.z + c.z + d2.z;
    r.w = a.w + b2.w + c.w + d2.w;
    *reinterpret_cast<float4*>(ctx_part + ((size_t)chunk * B + b) * H + tid * 4) = r;
  }
}

// ---------------- K5: x = concat(motion, context) @ pre_W^T + pre_b ----
__global__ __launch_bounds__(256) void k5_prelinear(
    const float* __restrict__ ctx_part, const float* __restrict__ motion,
    const float* __restrict__ pre_W, const float* __restrict__ pre_b,
    float* __restrict__ xpre) {
  int b = blockIdx.x;
  int g = threadIdx.x;
  __shared__ __align__(16) float cm[D + H];
  float c = 0.f;
#pragma unroll
  for (int p = 0; p < TCHUNK; ++p) c += ctx_part[((size_t)p * B + b) * H + g];
  cm[D + g] = c;
  if (g < D) cm[g] = motion[b * D + g];
  __syncthreads();
  const float4* cm4 = reinterpret_cast<const float4*>(cm);
  const float4* wr = reinterpret_cast<const float4*>(pre_W + (size_t)g * (D + H));
  float acc = pre_b[g];
#pragma unroll 8
  for (int j = 0; j < (D + H) / 4; ++j) {
    float4 w = wr[j], x = cm4[j];
    acc += w.x * x.x + w.y * x.y + w.z * x.z + w.w * x.w;
  }
  xpre[b * H + g] = acc;
}

// ---------------- K5b: batchnorm (over B) + relu ----
__global__ __launch_bounds__(256) void k5b_bn(
    const float* __restrict__ xpre, const float* __restrict__ gamma,
    const float* __restrict__ beta, float* __restrict__ xn) {
  int g = threadIdx.x;
  float mu = 0.f;
  for (int b = 0; b < B; ++b) mu += xpre[b * H + g];
  mu *= (1.f / B);
  float var = 0.f;
  for (int b = 0; b < B; ++b) {
    float d = xpre[b * H + g] - mu;
    var += d * d;
  }
  var *= (1.f / B);
  float sc = gamma[g] * rsqrtf(var + EPS);
  float bi = beta[g];
  for (int b = 0; b < B; ++b) {
    float y = (xpre[b * H + g] - mu) * sc + bi;
    xn[b * H + g] = fmaxf(y, 0.f);
  }
}

// ---------------- K6: GRU cell + output projection (fused) ----
__global__ __launch_bounds__(256) void k6_gru_out(
    const float* __restrict__ xn, const float* __restrict__ gh,
    const float* __restrict__ W_ih, const float* __restrict__ b_ih,
    const float* __restrict__ last_hidden, const float* __restrict__ out_W,
    const float* __restrict__ out_b, float* __restrict__ out_output,
    float* __restrict__ out_hidden) {
  int b = blockIdx.x;
  int g = threadIdx.x;
  __shared__ __align__(16) float xr[H];
  __shared__ __align__(16) float hn[H];
  xr[g] = xn[b * H + g];
  __syncthreads();
  const float4* xr4 = reinterpret_cast<const float4*>(xr);
  float gi[3];
#pragma unroll
  for (int k = 0; k < 3; ++k) {
    int row = k * H + g;
    const float4* wr = reinterpret_cast<const float4*>(W_ih + (size_t)row * H);
    float a = b_ih[row];
#pragma unroll 8
    for (int h4 = 0; h4 < H / 4; ++h4) {
      float4 w = wr[h4], x = xr4[h4];
      a += w.x * x.x + w.y * x.y + w.z * x.z + w.w * x.w;
    }
    gi[k] = a;
  }
  float hr = gh[(size_t)b * 3 * H + g];
  float hz = gh[(size_t)b * 3 * H + H + g];
  float hnn = gh[(size_t)b * 3 * H + 2 * H + g];
  float r = 1.f / (1.f + expf(-(gi[0] + hr)));
  float z = 1.f / (1.f + expf(-(gi[1] + hz)));
  float n = tanhf(gi[2] + r * hnn);
  float hprev = last_hidden[b * H + g];
  float hnew = (1.f - z) * n + z * hprev;
  out_hidden[b * H + g] = hnew;
  hn[g] = hnew;
  __syncthreads();
  if (g < O) {
    const float4* hn4 = reinterpret_cast<const float4*>(hn);
    const float4* wr = reinterpret_cast<const float4*>(out_W + (size_t)g * H);
    float a = out_b[g];
#pragma unroll 8
    for (int h4 = 0; h4 < H / 4; ++h4) {
      float4 w = wr[h4], x = hn4[h4];
      a += w.x * x.x + w.y * x.y + w.z * x.z + w.w * x.w;
    }
    out_output[b * O + g] = a;
  }
}

extern "C" void kernel_launch(void* const* d_in, const int* in_sizes, int n_in,
                              void* d_out, int out_size, void* d_ws,
                              size_t ws_size, hipStream_t stream) {
  (void)in_sizes; (void)n_in; (void)out_size; (void)ws_size;
  const float* motion      = (const float*)d_in[0];
  const float* last_hidden = (const float*)d_in[1];
  const float* enc         = (const float*)d_in[2];
  const float* attn_W      = (const float*)d_in[3];
  const float* attn_b      = (const float*)d_in[4];
  const float* v           = (const float*)d_in[5];
  const float* pre_W       = (const float*)d_in[6];
  const float* pre_b       = (const float*)d_in[7];
  const float* bn_g        = (const float*)d_in[8];
  const float* bn_b        = (const float*)d_in[9];
  const float* W_ih        = (const float*)d_in[10];
  const float* b_ih        = (const float*)d_in[11];
  const float* W_hh        = (const float*)d_in[12];
  const float* b_hh        = (const float*)d_in[13];
  const float* out_W       = (const float*)d_in[14];
  const float* out_b       = (const float*)d_in[15];

  float* out = (float*)d_out;
  float* out_output = out;                    // B*O
  float* out_hidden = out + B * O;            // B*H
  float* out_attn   = out + B * O + B * H;    // B*T

  float* ws = (float*)d_ws;
  float* sc = ws;                                   // B*T      = 262144
  float* cp = sc + (size_t)B * T;                   // 16*B*H   = 262144
  float* hp = cp + (size_t)TCHUNK * B * H;          // B*H      = 16384
  float* gh = hp + (size_t)B * H;                   // B*3H     = 49152
  float* xp = gh + (size_t)B * 3 * H;               // B*H      = 16384
  float* xn = xp + (size_t)B * H;                   // B*H      = 16384
  _Float16* Bperm = (_Float16*)(xn + (size_t)B * H); // H*H f16 = 128KB

  k0_permW<<<256, 256, 0, stream>>>(attn_W, Bperm);
  k1_hidproj_gh<<<B, 256, 0, stream>>>(last_hidden, attn_W, attn_b, W_hh, b_hh,
                                       hp, gh);
  k2_scores_mfma<<<dim3(T / TT, B), 256, 0, stream>>>(enc, Bperm, hp, v, sc);
  k3_softmax<<<B, 256, 0, stream>>>(sc, out_attn);
  k4_ctx_part<<<dim3(TCHUNK, B), 256, 0, stream>>>(enc, out_attn, cp);
  k5_prelinear<<<B, 256, 0, stream>>>(cp, motion, pre_W, pre_b, xp);
  k5b_bn<<<1, 256, 0, stream>>>(xp, bn_g, bn_b, xn);
  k6_gru_out<<<B, 256, 0, stream>>>(xn, gh, W_ih, b_ih, last_hidden, out_W,
                                    out_b, out_output, out_hidden);
}

// Round 7
// 210.119 us; speedup vs baseline: 4.4706x; 1.2365x over previous
//
#include <hip/hip_runtime.h>
#include <math.h>

#define B 64
#define T 4096
#define H 256
#define D 128
#define O 128
#define EPS 1e-5f

#define TT 64        // t-rows per block in scores kernel
#define TCHUNK 16    // t-chunks for context partials

typedef _Float16 half8 __attribute__((ext_vector_type(8)));
typedef float f32x4 __attribute__((ext_vector_type(4)));

__device__ __forceinline__ float tanh_fast(float x) {
  // 1 - 2/(e^{2x}+1): exp overflow -> 1, exp->0 -> -1 (no inf/inf NaN)
  return 1.f - 2.f / (__expf(2.f * x) + 1.f);
}

// ---------------- K0: permute W_e (= attn_W[:, H:]) into f16 MFMA-fragment order ----
// Bperm[(((nt*8)+kt)*64 + lane)*8 + j] = W_e[nt*16+(lane&15)][kt*32+(lane>>4)*8+j]
__global__ __launch_bounds__(256) void k0_permW(const float* __restrict__ attn_W,
                                               _Float16* __restrict__ Bperm) {
  int idx = blockIdx.x * 256 + threadIdx.x;  // 0..65535
  int j = idx & 7;
  int l = (idx >> 3) & 63;
  int kt = (idx >> 9) & 7;
  int nt = idx >> 12;
  int g = nt * 16 + (l & 15);
  int k = kt * 32 + ((l >> 4) << 3) + j;
  Bperm[idx] = (_Float16)attn_W[(size_t)g * (2 * H) + H + k];
}

// ---------------- K1: hid_proj = h_prev @ W_h^T + attn_b ; gh = h_prev @ W_hh^T + b_hh ----
__global__ __launch_bounds__(256) void k1_hidproj_gh(
    const float* __restrict__ last_hidden, const float* __restrict__ attn_W,
    const float* __restrict__ attn_b, const float* __restrict__ W_hh,
    const float* __restrict__ b_hh, float* __restrict__ hid_proj,
    float* __restrict__ gh) {
  int b = blockIdx.x;
  int g = threadIdx.x;  // 0..255
  __shared__ __align__(16) float hp[H];
  hp[g] = last_hidden[b * H + g];
  __syncthreads();
  const float4* hp4 = reinterpret_cast<const float4*>(hp);
  const float4* wr = reinterpret_cast<const float4*>(attn_W + (size_t)g * (2 * H));
  float acc = attn_b[g];
#pragma unroll 8
  for (int h4 = 0; h4 < H / 4; ++h4) {
    float4 w = wr[h4], x = hp4[h4];
    acc += w.x * x.x + w.y * x.y + w.z * x.z + w.w * x.w;
  }
  hid_proj[b * H + g] = acc;
#pragma unroll
  for (int k = 0; k < 3; ++k) {
    int row = k * H + g;
    const float4* whr = reinterpret_cast<const float4*>(W_hh + (size_t)row * H);
    float a2 = b_hh[row];
#pragma unroll 8
    for (int h4 = 0; h4 < H / 4; ++h4) {
      float4 w = whr[h4], x = hp4[h4];
      a2 += w.x * x.x + w.y * x.y + w.z * x.z + w.w * x.w;
    }
    gh[(size_t)b * (3 * H) + row] = a2;
  }
}

// ---------------- K2: MFMA scores. Per block: 64 t-rows x 256 g, K=256. ----
// Wave w owns g-tiles nt=4w..4w+3 (64 g) and ALL 4 m-tiles (64 t).
// enc tile staged once in LDS as f16 fragments; B from L2 (32KB/wave).
__global__ __launch_bounds__(256, 2) void k2_scores_mfma(
    const float* __restrict__ enc, const _Float16* __restrict__ Bperm,
    const float* __restrict__ hid_proj, const float* __restrict__ v,
    float* __restrict__ scores) {
  const int b = blockIdx.y;
  const int t0 = blockIdx.x * TT;
  const int tid = threadIdx.x;
  const int wave = tid >> 6;
  const int lane = tid & 63;
  const int r = lane & 15;    // fragment col (g) / A row (t)
  const int grp = lane >> 4;  // 0..3

  __shared__ __align__(16) _Float16 Alds[4 * 8 * 64 * 8];  // [m][kt][lane][8] = 32KB
  __shared__ float spart[4][TT];

  // ---- stage enc tile (64 rows x 256 k) -> f16 fragment order in LDS ----
  // chunk c = i*256 + tid: row = c>>5, kg = c&31 (8 k's each)
  {
    const int kg = tid & 31;
    const int rbase = tid >> 5;  // 0..7
    const int kt_s = kg >> 2;
    const int lhi = (kg & 3) << 4;
#pragma unroll
    for (int i = 0; i < 8; ++i) {
      int row = i * 8 + rbase;  // 0..63
      const float* src = enc + ((size_t)(t0 + row) * B + b) * H + kg * 8;
      float4 x0 = *reinterpret_cast<const float4*>(src);
      float4 x1 = *reinterpret_cast<const float4*>(src + 4);
      half8 hh;
      hh[0] = (_Float16)x0.x; hh[1] = (_Float16)x0.y;
      hh[2] = (_Float16)x0.z; hh[3] = (_Float16)x0.w;
      hh[4] = (_Float16)x1.x; hh[5] = (_Float16)x1.y;
      hh[6] = (_Float16)x1.z; hh[7] = (_Float16)x1.w;
      int m = row >> 4;
      int lane_s = lhi | (row & 15);
      *reinterpret_cast<half8*>(&Alds[(((m * 8) + kt_s) * 64 + lane_s) * 8]) = hh;
    }
  }
  __syncthreads();

  const half8* bp = reinterpret_cast<const half8*>(Bperm);
  const int ntb = wave * 4;

  f32x4 acc[4][4];
#pragma unroll
  for (int m = 0; m < 4; ++m)
#pragma unroll
    for (int n = 0; n < 4; ++n) acc[m][n] = (f32x4){0.f, 0.f, 0.f, 0.f};

  half8 bB[3][4];  // B 2-ahead (L2 latency ~200-300cy)
  half8 aA[2][4];  // A 1-ahead (LDS latency)
#pragma unroll
  for (int n = 0; n < 4; ++n) {
    bB[0][n] = bp[((ntb + n) * 8 + 0) * 64 + lane];
    bB[1][n] = bp[((ntb + n) * 8 + 1) * 64 + lane];
  }
#pragma unroll
  for (int m = 0; m < 4; ++m)
    aA[0][m] = *reinterpret_cast<const half8*>(&Alds[((m * 8 + 0) * 64 + lane) * 8]);

#pragma unroll
  for (int kt = 0; kt < 8; ++kt) {
    if (kt < 6) {
#pragma unroll
      for (int n = 0; n < 4; ++n)
        bB[(kt + 2) % 3][n] = bp[((ntb + n) * 8 + kt + 2) * 64 + lane];
    }
    if (kt < 7) {
#pragma unroll
      for (int m = 0; m < 4; ++m)
        aA[(kt + 1) & 1][m] =
            *reinterpret_cast<const half8*>(&Alds[((m * 8 + kt + 1) * 64 + lane) * 8]);
    }
#pragma unroll
    for (int m = 0; m < 4; ++m)
#pragma unroll
      for (int n = 0; n < 4; ++n)
        acc[m][n] = __builtin_amdgcn_mfma_f32_16x16x32_f16(
            aA[kt & 1][m], bB[kt % 3][n], acc[m][n], 0, 0, 0);
  }

  // ---- epilogue: v*tanh(energy + hid_proj) summed over this wave's 64 g ----
  float hpv[4], vg[4];
#pragma unroll
  for (int n = 0; n < 4; ++n) {
    int g = (ntb + n) * 16 + r;
    hpv[n] = hid_proj[b * H + g];
    vg[n] = v[g];
  }
#pragma unroll
  for (int m = 0; m < 4; ++m) {
#pragma unroll
    for (int i = 0; i < 4; ++i) {
      float s = 0.f;
#pragma unroll
      for (int n = 0; n < 4; ++n)
        s += vg[n] * tanh_fast(acc[m][n][i] + hpv[n]);
      s += __shfl_xor(s, 1);
      s += __shfl_xor(s, 2);
      s += __shfl_xor(s, 4);
      s += __shfl_xor(s, 8);
      if (r == 0) spart[wave][m * 16 + grp * 4 + i] = s;
    }
  }
  __syncthreads();
  if (tid < TT) {
    float sv = spart[0][tid] + spart[1][tid] + spart[2][tid] + spart[3][tid];
    scores[(size_t)b * T + t0 + tid] = sv;
  }
}

// ---------------- K3: softmax over T per b; writes attn_weights to output ----
__global__ __launch_bounds__(256) void k3_softmax(
    const float* __restrict__ scores, float* __restrict__ attn_out) {
  int b = blockIdx.x;
  int tid = threadIdx.x;
  float vals[16];
  const float4* sp = reinterpret_cast<const float4*>(scores + (size_t)b * T);
#pragma unroll
  for (int i = 0; i < 4; ++i) {
    float4 x = sp[i * 256 + tid];
    vals[i * 4 + 0] = x.x; vals[i * 4 + 1] = x.y;
    vals[i * 4 + 2] = x.z; vals[i * 4 + 3] = x.w;
  }
  float m = -INFINITY;
#pragma unroll
  for (int i = 0; i < 16; ++i) m = fmaxf(m, vals[i]);
  for (int off = 32; off > 0; off >>= 1) m = fmaxf(m, __shfl_xor(m, off));
  __shared__ float redm[4];
  int wave = tid >> 6, lane = tid & 63;
  if (lane == 0) redm[wave] = m;
  __syncthreads();
  m = fmaxf(fmaxf(redm[0], redm[1]), fmaxf(redm[2], redm[3]));
  float s = 0.f;
#pragma unroll
  for (int i = 0; i < 16; ++i) {
    vals[i] = expf(vals[i] - m);
    s += vals[i];
  }
  for (int off = 32; off > 0; off >>= 1) s += __shfl_xor(s, off);
  __shared__ float reds[4];
  if (lane == 0) reds[wave] = s;
  __syncthreads();
  s = reds[0] + reds[1] + reds[2] + reds[3];
  float inv = 1.f / s;
  float4* op = reinterpret_cast<float4*>(attn_out + (size_t)b * T);
#pragma unroll
  for (int i = 0; i < 4; ++i) {
    float4 x;
    x.x = vals[i * 4 + 0] * inv; x.y = vals[i * 4 + 1] * inv;
    x.z = vals[i * 4 + 2] * inv; x.w = vals[i * 4 + 3] * inv;
    op[i * 256 + tid] = x;
  }
}

// ---------------- K4: context partials over t-chunks ----
__global__ __launch_bounds__(256) void k4_ctx_part(
    const float* __restrict__ enc, const float* __restrict__ attn_w,
    float* __restrict__ ctx_part) {
  int chunk = blockIdx.x;
  int b = blockIdx.y;
  int tid = threadIdx.x;
  int h4 = tid & 63;
  int tsub = tid >> 6;  // 0..3
  int tstart = chunk * (T / TCHUNK);
  float4 acc = {0.f, 0.f, 0.f, 0.f};
  const float* wrow = attn_w + (size_t)b * T;
  for (int t = tstart + tsub; t < tstart + T / TCHUNK; t += 4) {
    float w = wrow[t];
    float4 e = *reinterpret_cast<const float4*>(
        enc + ((size_t)t * B + b) * H + h4 * 4);
    acc.x += w * e.x; acc.y += w * e.y; acc.z += w * e.z; acc.w += w * e.w;
  }
  __shared__ float4 red[4][64];
  red[tsub][h4] = acc;
  __syncthreads();
  if (tid < 64) {
    float4 a = red[0][tid], b2 = red[1][tid], c = red[2][tid], d2 = red[3][tid];
    float4 r;
    r.x = a.x + b2.x + c.x + d2.x;
    r.y = a.y + b2.y + c.y + d2.y;
    r.z = a.z + b2.z + c.z + d2.z;
    r.w = a.w + b2.w + c.w + d2.w;
    *reinterpret_cast<float4*>(ctx_part + ((size_t)chunk * B + b) * H + tid * 4) = r;
  }
}

// ---------------- K5: x = concat(motion, context) @ pre_W^T + pre_b ----
__global__ __launch_bounds__(256) void k5_prelinear(
    const float* __restrict__ ctx_part, const float* __restrict__ motion,
    const float* __restrict__ pre_W, const float* __restrict__ pre_b,
    float* __restrict__ xpre) {
  int b = blockIdx.x;
  int g = threadIdx.x;
  __shared__ __align__(16) float cm[D + H];
  float c = 0.f;
#pragma unroll
  for (int p = 0; p < TCHUNK; ++p) c += ctx_part[((size_t)p * B + b) * H + g];
  cm[D + g] = c;
  if (g < D) cm[g] = motion[b * D + g];
  __syncthreads();
  const float4* cm4 = reinterpret_cast<const float4*>(cm);
  const float4* wr = reinterpret_cast<const float4*>(pre_W + (size_t)g * (D + H));
  float acc = pre_b[g];
#pragma unroll 8
  for (int j = 0; j < (D + H) / 4; ++j) {
    float4 w = wr[j], x = cm4[j];
    acc += w.x * x.x + w.y * x.y + w.z * x.z + w.w * x.w;
  }
  xpre[b * H + g] = acc;
}

// ---------------- K5b: batchnorm (over B) + relu ----
__global__ __launch_bounds__(256) void k5b_bn(
    const float* __restrict__ xpre, const float* __restrict__ gamma,
    const float* __restrict__ beta, float* __restrict__ xn) {
  int g = threadIdx.x;
  float mu = 0.f;
  for (int b = 0; b < B; ++b) mu += xpre[b * H + g];
  mu *= (1.f / B);
  float var = 0.f;
  for (int b = 0; b < B; ++b) {
    float d = xpre[b * H + g] - mu;
    var += d * d;
  }
  var *= (1.f / B);
  float sc = gamma[g] * rsqrtf(var + EPS);
  float bi = beta[g];
  for (int b = 0; b < B; ++b) {
    float y = (xpre[b * H + g] - mu) * sc + bi;
    xn[b * H + g] = fmaxf(y, 0.f);
  }
}

// ---------------- K6: GRU cell + output projection (fused) ----
__global__ __launch_bounds__(256) void k6_gru_out(
    const float* __restrict__ xn, const float* __restrict__ gh,
    const float* __restrict__ W_ih, const float* __restrict__ b_ih,
    const float* __restrict__ last_hidden, const float* __restrict__ out_W,
    const float* __restrict__ out_b, float* __restrict__ out_output,
    float* __restrict__ out_hidden) {
  int b = blockIdx.x;
  int g = threadIdx.x;
  __shared__ __align__(16) float xr[H];
  __shared__ __align__(16) float hn[H];
  xr[g] = xn[b * H + g];
  __syncthreads();
  const float4* xr4 = reinterpret_cast<const float4*>(xr);
  float gi[3];
#pragma unroll
  for (int k = 0; k < 3; ++k) {
    int row = k * H + g;
    const float4* wr = reinterpret_cast<const float4*>(W_ih + (size_t)row * H);
    float a = b_ih[row];
#pragma unroll 8
    for (int h4 = 0; h4 < H / 4; ++h4) {
      float4 w = wr[h4], x = xr4[h4];
      a += w.x * x.x + w.y * x.y + w.z * x.z + w.w * x.w;
    }
    gi[k] = a;
  }
  float hr = gh[(size_t)b * 3 * H + g];
  float hz = gh[(size_t)b * 3 * H + H + g];
  float hnn = gh[(size_t)b * 3 * H + 2 * H + g];
  float r = 1.f / (1.f + expf(-(gi[0] + hr)));
  float z = 1.f / (1.f + expf(-(gi[1] + hz)));
  float n = tanhf(gi[2] + r * hnn);
  float hprev = last_hidden[b * H + g];
  float hnew = (1.f - z) * n + z * hprev;
  out_hidden[b * H + g] = hnew;
  hn[g] = hnew;
  __syncthreads();
  if (g < O) {
    const float4* hn4 = reinterpret_cast<const float4*>(hn);
    const float4* wr = reinterpret_cast<const float4*>(out_W + (size_t)g * H);
    float a = out_b[g];
#pragma unroll 8
    for (int h4 = 0; h4 < H / 4; ++h4) {
      float4 w = wr[h4], x = hn4[h4];
      a += w.x * x.x + w.y * x.y + w.z * x.z + w.w * x.w;
    }
    out_output[b * O + g] = a;
  }
}

extern "C" void kernel_launch(void* const* d_in, const int* in_sizes, int n_in,
                              void* d_out, int out_size, void* d_ws,
                              size_t ws_size, hipStream_t stream) {
  (void)in_sizes; (void)n_in; (void)out_size; (void)ws_size;
  const float* motion      = (const float*)d_in[0];
  const float* last_hidden = (const float*)d_in[1];
  const float* enc         = (const float*)d_in[2];
  const float* attn_W      = (const float*)d_in[3];
  const float* attn_b      = (const float*)d_in[4];
  const float* v           = (const float*)d_in[5];
  const float* pre_W       = (const float*)d_in[6];
  const float* pre_b       = (const float*)d_in[7];
  const float* bn_g        = (const float*)d_in[8];
  const float* bn_b        = (const float*)d_in[9];
  const float* W_ih        = (const float*)d_in[10];
  const float* b_ih        = (const float*)d_in[11];
  const float* W_hh        = (const float*)d_in[12];
  const float* b_hh        = (const float*)d_in[13];
  const float* out_W       = (const float*)d_in[14];
  const float* out_b       = (const float*)d_in[15];

  float* out = (float*)d_out;
  float* out_output = out;                    // B*O
  float* out_hidden = out + B * O;            // B*H
  float* out_attn   = out + B * O + B * H;    // B*T

  float* ws = (float*)d_ws;
  float* sc = ws;                                   // B*T      = 262144
  float* cp = sc + (size_t)B * T;                   // 16*B*H   = 262144
  float* hp = cp + (size_t)TCHUNK * B * H;          // B*H      = 16384
  float* gh = hp + (size_t)B * H;                   // B*3H     = 49152
  float* xp = gh + (size_t)B * 3 * H;               // B*H      = 16384
  float* xn = xp + (size_t)B * H;                   // B*H      = 16384
  _Float16* Bperm = (_Float16*)(xn + (size_t)B * H); // H*H f16 = 128KB

  k0_permW<<<256, 256, 0, stream>>>(attn_W, Bperm);
  k1_hidproj_gh<<<B, 256, 0, stream>>>(last_hidden, attn_W, attn_b, W_hh, b_hh,
                                       hp, gh);
  k2_scores_mfma<<<dim3(T / TT, B), 256, 0, stream>>>(enc, Bperm, hp, v, sc);
  k3_softmax<<<B, 256, 0, stream>>>(sc, out_attn);
  k4_ctx_part<<<dim3(TCHUNK, B), 256, 0, stream>>>(enc, out_attn, cp);
  k5_prelinear<<<B, 256, 0, stream>>>(cp, motion, pre_W, pre_b, xp);
  k5b_bn<<<1, 256, 0, stream>>>(xp, bn_g, bn_b, xn);
  k6_gru_out<<<B, 256, 0, stream>>>(xn, gh, W_ih, b_ih, last_hidden, out_W,
                                    out_b, out_output, out_hidden);
}